// Round 17
// baseline (6867.516 us; speedup 1.0000x reference)
//
#include <hip/hip_runtime.h>
#include <hip/hip_fp16.h>

#define BB 128
#define II 64
#define SS 2048
#define HH 128
#define GG 512   // 4*H
#define OO 64
#define TT 32    // x time-tile width (fallback kernel)
#define TCH 128  // precompute t-chunk
#define XPBYTES ((size_t)BB * SS * GG * 2)

typedef _Float16 f16x2 __attribute__((ext_vector_type(2)));
union F4H { float4 f4; f16x2 h[4]; };

__device__ __forceinline__ f16x2 pack2(float a, float b) {
    f16x2 r; r.x = (_Float16)a; r.y = (_Float16)b; return r;
}

__device__ __forceinline__ float dot2(f16x2 w, f16x2 v, float c) {
#if __has_builtin(__builtin_amdgcn_fdot2)
    return __builtin_amdgcn_fdot2(w, v, c, false);
#else
    return fmaf((float)w.x, (float)v.x, fmaf((float)w.y, (float)v.y, c));
#endif
}

__device__ __forceinline__ float sigm(float v) {
    return __builtin_amdgcn_rcpf(1.0f + __expf(-v));
}
// original tanh (fallback kernel keeps R1 bit-exact behavior)
__device__ __forceinline__ float tanh_f(float v) {
    float a = fabsf(v);
    float e = __expf(-2.0f * a);
    float r = (1.0f - e) * __builtin_amdgcn_rcpf(1.0f + e);
    return v < 0.0f ? -r : r;
}
// branch-free tanh = 2*sigm(2v)-1 (safe at +/-inf)
__device__ __forceinline__ float tanh_c(float v) {
    return fmaf(2.0f, __builtin_amdgcn_rcpf(1.0f + __expf(-2.0f * v)), -1.0f);
}

// quad-scope shuffle via DPP quad_perm (VALU pipe ~4cyc)
template <int CTRL>
__device__ __forceinline__ float qdpp(float x) {
    return __int_as_float(__builtin_amdgcn_update_dpp(
        0, __float_as_int(x), CTRL, 0xF, 0xF, true));
}
#define QP_XOR3 0x1B   // [3,2,1,0]
#define QP_BC0  0x00   // [0,0,0,0]
#define QP_BC1  0x55   // [1,1,1,1]
#define QP_BC2  0xAA   // [2,2,2,2]

// LDS-only barrier (R15, null-to-positive vs __syncthreads): lgkmcnt(0) +
// raw s_barrier, no vmcnt drain — global loads/stores stay in flight.
__device__ __forceinline__ void lds_barrier() {
    asm volatile("s_waitcnt lgkmcnt(0)" ::: "memory");
    __builtin_amdgcn_s_barrier();
}

// ============================================================================
// XP precompute: XP[b][t][j] = sum_i x[b,i,t] * Wx_out[i,j], stored f16.
// ============================================================================
__global__ void __launch_bounds__(512)
xp_gemm(const float* __restrict__ x, const float* __restrict__ Wx_out,
        _Float16* __restrict__ xp)
{
    const int tc = blockIdx.x;          // 0..15
    const int b  = blockIdx.y;          // 0..127
    const int j  = threadIdx.x;         // gate column 0..511
    const int t0 = tc * TCH;

    __shared__ __align__(16) f16x2 x2s[TCH][36];

    f16x2 w2[32];
#pragma unroll
    for (int c = 0; c < 32; ++c)
        w2[c] = pack2(Wx_out[(2 * c) * GG + j], Wx_out[(2 * c + 1) * GG + j]);

    const float* xrow = x + (size_t)b * II * SS;
    const int r = j >> 3;
#pragma unroll
    for (int rep = 0; rep < 4; ++rep) {
        const int u = (j & 7) + 8 * rep;
        const float4 v = *(const float4*)(xrow + (size_t)r * SS + t0 + 4 * u);
        const int c = r >> 1, half = r & 1;
        ((_Float16*)&x2s[4 * u + 0][c])[half] = (_Float16)v.x;
        ((_Float16*)&x2s[4 * u + 1][c])[half] = (_Float16)v.y;
        ((_Float16*)&x2s[4 * u + 2][c])[half] = (_Float16)v.z;
        ((_Float16*)&x2s[4 * u + 3][c])[half] = (_Float16)v.w;
    }
    __syncthreads();

    _Float16* xpo = xp + ((size_t)b * SS + t0) * GG + j;
#pragma unroll 4
    for (int tt = 0; tt < TCH; ++tt) {
        const float4* xr4 = (const float4*)&x2s[tt][0];
        float a0 = 0.f, a1 = 0.f;
#pragma unroll
        for (int q = 0; q < 8; ++q) {
            F4H u; u.f4 = xr4[q];
            a0 = dot2(w2[4 * q + 0], u.h[0], a0);
            a1 = dot2(w2[4 * q + 1], u.h[1], a1);
            a0 = dot2(w2[4 * q + 2], u.h[2], a0);
            a1 = dot2(w2[4 * q + 3], u.h[3], a1);
        }
        xpo[(size_t)tt * GG] = (_Float16)(a0 + a1);
    }
}

// ============================================================================
// Scan — TWO BATCHES PER BLOCK, UNSKEWED (64 blocks x 512 threads).
// (Resubmission of R16 — container died before measurement; kernel audited:
// uniform barriers, no spin-waits, LDS 146/160 KB — nothing hangs.)
// Both batches execute the SAME phase simultaneously: their dot2s are
// independent and interleave (ILP fills dependency stalls), and the
// barrier/chain latency (~2800 of 4113 cyc/step in R12) is amortized 2x.
// Contrast R4 (skewed heavy||heavy in one PC, 11300us): here issue/wave is
// ~1200 cyc for TWO batch-steps, not 2x serial phases.
// ENABLER: who -> LDS (whoL, R10's verified conflict-free layout; -4%
// standalone) frees 64 weight regs so the 2nd batch's ~10 live values fit
// UNDER the R8/R11 spill cliff (phase-C demand ~175 vs the ~222 that works).
// whoL/wlf reads are SHARED by both batches (read once, dot twice).
// DO-NOT-TOUCH (measured): E placement post-S2 only (R13: 2.6x else);
// no extra live state across phase C beyond this budget (R8/R11 spill).
// Watchdog: FETCH must stay ~173 MB.
// ============================================================================
__global__ void __launch_bounds__(512)
nlstm_scan_xp2(
    const _Float16* __restrict__ xp,
    const float* __restrict__ Wh_out, const float* __restrict__ b_out,
    const float* __restrict__ Wx_in, const float* __restrict__ Wh_in,
    const float* __restrict__ b_in,
    const float* __restrict__ W_lin, const float* __restrict__ b_lin,
    float* __restrict__ out)
{
    const int blk = blockIdx.x;       // 0..63
    const int b0  = 2 * blk;
    const int b1  = 2 * blk + 1;
    const int j   = threadIdx.x;
    const int g   = j & 3;            // gate lane within quad: 0=i 1=f 2=o 3=g
    const int m   = j >> 2;           // h-column 0..127
    const int col = g * 128 + m;      // gate column in canonical layout

    __shared__ __align__(16) float4 whoL[16 * 512];    // Wh_out fp16, 128 KB
    __shared__ __align__(16) float4 wlf[16 * 66];      // W_lin fp16, 16.5 KB
    __shared__ __align__(16) _Float16 hb0s[HH],  hb1s[HH];
    __shared__ __align__(16) _Float16 xib0[HH],  xib1[HH];
    __shared__ __align__(16) _Float16 hib0[HH],  hib1[HH];

    // register-resident inner weights (column col) : 128 regs
    f16x2 wxi[HH / 2], whi[HH / 2];
#pragma unroll
    for (int q = 0; q < HH / 2; ++q)
        wxi[q] = pack2(Wx_in[(2 * q) * GG + col], Wx_in[(2 * q + 1) * GG + col]);
#pragma unroll
    for (int q = 0; q < HH / 2; ++q)
        whi[q] = pack2(Wh_in[(2 * q) * GG + col], Wh_in[(2 * q + 1) * GG + col]);

    // Wh_out -> LDS fp16 (thread j stages its own column's 16 chunks;
    // whoL[c*512+j] is R10's verified conflict-free layout)
#pragma unroll
    for (int c = 0; c < 16; ++c) {
        F4H u;
#pragma unroll
        for (int q = 0; q < 4; ++q)
            u.h[q] = pack2(Wh_out[(8 * c + 2 * q) * GG + col],
                           Wh_out[(8 * c + 2 * q + 1) * GG + col]);
        whoL[c * 512 + j] = u.f4;
    }

    const float bo = b_out[col];
    const float bi = b_in[col];
    // branch-free activation: g<3 -> sigm(x); g==3 -> tanh(x)=2*sigm(2x)-1
    const float kk = (g == 3) ? 2.0f : 1.0f;
    const float aa = (g == 3) ? 2.0f : 1.0f;
    const float cc = (g == 3) ? -1.0f : 0.0f;

    const int   pn = j >> 3;
    const int   ps = j & 7;
    const float bl = b_lin[pn];

    // W_lin -> LDS fp16 (1024 chunks, 2 per thread)
#pragma unroll
    for (int r = 0; r < 2; ++r) {
        const int mm = r * 512 + j;
        const int c = mm >> 6, n = mm & 63;
        F4H u;
#pragma unroll
        for (int q = 0; q < 4; ++q)
            u.h[q] = pack2(W_lin[n * HH + 8 * c + 2 * q],
                           W_lin[n * HH + 8 * c + 2 * q + 1]);
        wlf[c * 66 + n] = u.f4;
    }

    if (j < HH) {
        hb0s[j] = (_Float16)0.f; hb1s[j] = (_Float16)0.f;
        xib0[j] = (_Float16)0.f; xib1[j] = (_Float16)0.f;
        hib0[j] = (_Float16)0.f; hib1[j] = (_Float16)0.f;
    }
    float c_reg0 = 0.f, cn_reg0 = 0.f, o_all0 = 0.f;
    float c_reg1 = 0.f, cn_reg1 = 0.f, o_all1 = 0.f;
    __syncthreads();

    const _Float16* xpr0 = xp + (size_t)b0 * SS * GG + col;
    const _Float16* xpr1 = xp + (size_t)b1 * SS * GG + col;
    float* orow0 = out + (size_t)b0 * SS * OO;
    float* orow1 = out + (size_t)b1 * SS * OO;
    const float4* hb40 = (const float4*)hb0s;   // 16 chunks
    const float4* hb41 = (const float4*)hb1s;
    const float4* xi40 = (const float4*)xib0;
    const float4* xi41 = (const float4*)xib1;
    const float4* hi40 = (const float4*)hib0;
    const float4* hi41 = (const float4*)hib1;

    _Float16 xpc0 = xpr0[0];
    _Float16 xpc1 = xpr1[0];

#pragma unroll 1
    for (int t = 0; t < SS; ++t) {
        // ---- phase A: outer gates, both batches (weights read ONCE) ----
        float aA0 = bo + (float)xpc0, aA1 = 0.f, aA2 = 0.f, aA3 = 0.f;
        float aB0 = bo + (float)xpc1, aB1 = 0.f, aB2 = 0.f, aB3 = 0.f;
#pragma unroll
        for (int c = 0; c < 16; ++c) {
            F4H wu; wu.f4 = whoL[c * 512 + j];
            F4H h0; h0.f4 = hb40[c];
            F4H h1; h1.f4 = hb41[c];
            aA0 = dot2(wu.h[0], h0.h[0], aA0);
            aB0 = dot2(wu.h[0], h1.h[0], aB0);
            aA1 = dot2(wu.h[1], h0.h[1], aA1);
            aB1 = dot2(wu.h[1], h1.h[1], aB1);
            aA2 = dot2(wu.h[2], h0.h[2], aA2);
            aB2 = dot2(wu.h[2], h1.h[2], aB2);
            aA3 = dot2(wu.h[3], h0.h[3], aA3);
            aB3 = dot2(wu.h[3], h1.h[3], aB3);
        }
        // prefetch next step's XP (stays in flight across S1)
        const _Float16 xpn0 = xpr0[(size_t)((t + 1) & (SS - 1)) * GG];
        const _Float16 xpn1 = xpr1[(size_t)((t + 1) & (SS - 1)) * GG];
        const float accA = (aA0 + aA1) + (aA2 + aA3);
        const float accB = (aB0 + aB1) + (aB2 + aB3);
        const float vA = fmaf(aa, sigm(kk * accA), cc);
        const float vB = fmaf(aa, sigm(kk * accB), cc);
        const float vg3A = qdpp<QP_XOR3>(vA);
        const float vg3B = qdpp<QP_XOR3>(vB);
        o_all0 = qdpp<QP_BC2>(vA);
        o_all1 = qdpp<QP_BC2>(vB);
        if (g == 0) {
            xib0[m] = (_Float16)(vA * vg3A);
            xib1[m] = (_Float16)(vB * vg3B);
        } else if (g == 1) {
            hib0[m] = (_Float16)(vA * c_reg0);
            hib1[m] = (_Float16)(vB * c_reg1);
        }
        lds_barrier();   // S1

        // ---- phase C: inner gates, both batches (reg weights shared) ----
        float cA0 = bi, cA1 = 0.f, cA2 = 0.f, cA3 = 0.f;
        float cB0 = bi, cB1 = 0.f, cB2 = 0.f, cB3 = 0.f;
#pragma unroll
        for (int c = 0; c < 16; ++c) {
            F4H x0; x0.f4 = xi40[c];
            F4H x1; x1.f4 = xi41[c];
            cA0 = dot2(wxi[4 * c + 0], x0.h[0], cA0);
            cB0 = dot2(wxi[4 * c + 0], x1.h[0], cB0);
            cA1 = dot2(wxi[4 * c + 1], x0.h[1], cA1);
            cB1 = dot2(wxi[4 * c + 1], x1.h[1], cB1);
            cA2 = dot2(wxi[4 * c + 2], x0.h[2], cA2);
            cB2 = dot2(wxi[4 * c + 2], x1.h[2], cB2);
            cA3 = dot2(wxi[4 * c + 3], x0.h[3], cA3);
            cB3 = dot2(wxi[4 * c + 3], x1.h[3], cB3);
        }
#pragma unroll
        for (int c = 0; c < 16; ++c) {
            F4H h0; h0.f4 = hi40[c];
            F4H h1; h1.f4 = hi41[c];
            cA0 = dot2(whi[4 * c + 0], h0.h[0], cA0);
            cB0 = dot2(whi[4 * c + 0], h1.h[0], cB0);
            cA1 = dot2(whi[4 * c + 1], h0.h[1], cA1);
            cB1 = dot2(whi[4 * c + 1], h1.h[1], cB1);
            cA2 = dot2(whi[4 * c + 2], h0.h[2], cA2);
            cB2 = dot2(whi[4 * c + 2], h1.h[2], cB2);
            cA3 = dot2(whi[4 * c + 3], h0.h[3], cA3);
            cB3 = dot2(whi[4 * c + 3], h1.h[3], cB3);
        }
        const float accCA = (cA0 + cA1) + (cA2 + cA3);
        const float accCB = (cB0 + cB1) + (cB2 + cB3);
        const float uA = fmaf(aa, sigm(kk * accCA), cc);
        const float uB = fmaf(aa, sigm(kk * accCB), cc);
        // DPP tails, both batches (independent broadcasts)
        {
            const float ug3A = qdpp<QP_XOR3>(uA);
            const float ug3B = qdpp<QP_XOR3>(uB);
            const float p0A = uA * ug3A;
            const float p0B = uB * ug3B;
            const float PA = qdpp<QP_BC0>(p0A);
            const float PB = qdpp<QP_BC0>(p0B);
            const float FA = qdpp<QP_BC1>(uA);
            const float FB = qdpp<QP_BC1>(uB);
            const float OA = qdpp<QP_BC2>(uA);
            const float OB = qdpp<QP_BC2>(uB);
            const float cnA = fmaf(FA, cn_reg0, PA);
            const float cnB = fmaf(FB, cn_reg1, PB);
            cn_reg0 = cnA; cn_reg1 = cnB;
            const float cA = OA * tanh_c(cnA);
            const float cB = OB * tanh_c(cnB);
            c_reg0 = cA; c_reg1 = cB;
            const float hA = o_all0 * tanh_c(cA);
            const float hB = o_all1 * tanh_c(cB);
            if (g == 2) { hb0s[m] = (_Float16)hA; hb1s[m] = (_Float16)hB; }
        }
        xpc0 = xpn0; xpc1 = xpn1;
        lds_barrier();   // S2

        // ---- phase E: fused projections (post-S2 — R13-proven placement) ----
        float pA = 0.f, pB = 0.f;
#pragma unroll
        for (int q = 0; q < 2; ++q) {
            const int c = 2 * ps + q;
            F4H wu; wu.f4 = wlf[c * 66 + pn];
            F4H h0; h0.f4 = hb40[c];
            F4H h1; h1.f4 = hb41[c];
            pA = dot2(wu.h[0], h0.h[0], pA);
            pB = dot2(wu.h[0], h1.h[0], pB);
            pA = dot2(wu.h[1], h0.h[1], pA);
            pB = dot2(wu.h[1], h1.h[1], pB);
            pA = dot2(wu.h[2], h0.h[2], pA);
            pB = dot2(wu.h[2], h1.h[2], pB);
            pA = dot2(wu.h[3], h0.h[3], pA);
            pB = dot2(wu.h[3], h1.h[3], pB);
        }
        pA += __shfl_down(pA, 4, 8);
        pB += __shfl_down(pB, 4, 8);
        pA += __shfl_down(pA, 2, 8);
        pB += __shfl_down(pB, 2, 8);
        pA += __shfl_down(pA, 1, 8);
        pB += __shfl_down(pB, 1, 8);
        if (ps == 0) {
            orow0[t * OO + pn] = pA + bl;
            orow1[t * OO + pn] = pB + bl;
        }
    }
}

// ============================================================================
// FALLBACK: exact R1 kernel (measured 4364 us) for when ws is too small.
// ============================================================================
__global__ void
__attribute__((amdgpu_flat_work_group_size(512, 512)))
__attribute__((amdgpu_waves_per_eu(2, 2)))
nlstm_scan(
    const float* __restrict__ x,
    const float* __restrict__ Wx_out, const float* __restrict__ Wh_out,
    const float* __restrict__ b_out,
    const float* __restrict__ Wx_in, const float* __restrict__ Wh_in,
    const float* __restrict__ b_in,
    const float* __restrict__ W_lin, const float* __restrict__ b_lin,
    float* __restrict__ out)
{
    const int b = blockIdx.x;
    const int j = threadIdx.x;

    __shared__ __align__(16) float4 wxf[8 * 512];
    __shared__ __align__(16) float4 wlf[16 * 66];
    __shared__ float xt[2][II][TT + 1];
    __shared__ __align__(16) f16x2 xb[2][II / 2];
    __shared__ __align__(16) f16x2 hb[HH / 2];
    __shared__ __align__(16) f16x2 xib[HH / 2];
    __shared__ __align__(16) f16x2 hib[HH / 2];
    __shared__ float cb[HH];
    __shared__ float cnb[HH];
    __shared__ float actO[GG];
    __shared__ float actI[GG];

    f16x2 who[HH / 2], wxi[HH / 2], whi[HH / 2];
#pragma unroll
    for (int m = 0; m < HH / 2; ++m)
        who[m] = pack2(Wh_out[(2 * m) * GG + j], Wh_out[(2 * m + 1) * GG + j]);
#pragma unroll
    for (int m = 0; m < HH / 2; ++m)
        wxi[m] = pack2(Wx_in[(2 * m) * GG + j], Wx_in[(2 * m + 1) * GG + j]);
#pragma unroll
    for (int m = 0; m < HH / 2; ++m)
        whi[m] = pack2(Wh_in[(2 * m) * GG + j], Wh_in[(2 * m + 1) * GG + j]);

    const float bo = b_out[j];
    const float bi = b_in[j];
    const int   pn = j >> 3;
    const int   ps = j & 7;
    const float bl = b_lin[pn];

#pragma unroll
    for (int c = 0; c < 8; ++c) {
        F4H u;
#pragma unroll
        for (int q = 0; q < 4; ++q)
            u.h[q] = pack2(Wx_out[(8 * c + 2 * q) * GG + j],
                           Wx_out[(8 * c + 2 * q + 1) * GG + j]);
        wxf[c * 512 + j] = u.f4;
    }
#pragma unroll
    for (int r = 0; r < 2; ++r) {
        const int m = r * 512 + j;
        const int c = m >> 6, n = m & 63;
        F4H u;
#pragma unroll
        for (int q = 0; q < 4; ++q)
            u.h[q] = pack2(W_lin[n * HH + 8 * c + 2 * q],
                           W_lin[n * HH + 8 * c + 2 * q + 1]);
        wlf[c * 66 + n] = u.f4;
    }

    const float* xrow = x + (size_t)b * II * SS;
    float* orow = out + (size_t)b * SS * OO;

    {
        const int row = j >> 3, tc = j & 7;
        const float4 v = *(const float4*)(xrow + (size_t)row * SS + 4 * tc);
        float* dst = &xt[0][row][4 * tc];
        dst[0] = v.x; dst[1] = v.y; dst[2] = v.z; dst[3] = v.w;
    }
    if (j < HH / 2) hb[j] = pack2(0.f, 0.f);
    if (j < HH) { cb[j] = 0.f; cnb[j] = 0.f; }
    if (j >= 256 && j < 256 + 32) {
        const int m = j - 256;
        xb[0][m] = pack2(xrow[(2 * m) * SS], xrow[(2 * m + 1) * SS]);
    }
    __syncthreads();

    const float4* hb4 = (const float4*)hb;
    const float4* xi4 = (const float4*)xib;
    const float4* hi4 = (const float4*)hib;

#pragma unroll 1
    for (int t = 0; t < SS; ++t) {
        const float4* xcur = (const float4*)xb[t & 1];
        float a0 = bo, a1 = 0.f, a2 = 0.f, a3 = 0.f;
#pragma unroll
        for (int c = 0; c < 8; ++c) {
            F4H xu; xu.f4 = xcur[c];
            F4H wu; wu.f4 = wxf[c * 512 + j];
            a0 = dot2(wu.h[0], xu.h[0], a0);
            a1 = dot2(wu.h[1], xu.h[1], a1);
            a2 = dot2(wu.h[2], xu.h[2], a2);
            a3 = dot2(wu.h[3], xu.h[3], a3);
        }
#pragma unroll
        for (int c = 0; c < 16; ++c) {
            F4H hu; hu.f4 = hb4[c];
            a0 = dot2(who[4 * c + 0], hu.h[0], a0);
            a1 = dot2(who[4 * c + 1], hu.h[1], a1);
            a2 = dot2(who[4 * c + 2], hu.h[2], a2);
            a3 = dot2(who[4 * c + 3], hu.h[3], a3);
        }
        {
            const float acc = (a0 + a1) + (a2 + a3);
            actO[j] = (j < 384) ? sigm(acc) : tanh_f(acc);
        }
        __syncthreads();

        if (j < II) {
            xib[j] = pack2(actO[2 * j] * actO[384 + 2 * j],
                           actO[2 * j + 1] * actO[384 + 2 * j + 1]);
        } else if (j < II + HH / 2) {
            const int m = j - II;
            hib[m] = pack2(actO[HH + 2 * m] * cb[2 * m],
                           actO[HH + 2 * m + 1] * cb[2 * m + 1]);
        }
        __syncthreads();

        float c0 = bi, c1 = 0.f, c2 = 0.f, c3 = 0.f;
#pragma unroll
        for (int c = 0; c < 16; ++c) {
            F4H xu; xu.f4 = xi4[c];
            c0 = dot2(wxi[4 * c + 0], xu.h[0], c0);
            c1 = dot2(wxi[4 * c + 1], xu.h[1], c1);
            c2 = dot2(wxi[4 * c + 2], xu.h[2], c2);
            c3 = dot2(wxi[4 * c + 3], xu.h[3], c3);
        }
#pragma unroll
        for (int c = 0; c < 16; ++c) {
            F4H hu; hu.f4 = hi4[c];
            c0 = dot2(whi[4 * c + 0], hu.h[0], c0);
            c1 = dot2(whi[4 * c + 1], hu.h[1], c1);
            c2 = dot2(whi[4 * c + 2], hu.h[2], c2);
            c3 = dot2(whi[4 * c + 3], hu.h[3], c3);
        }
        {
            const float acc2 = (c0 + c1) + (c2 + c3);
            actI[j] = (j < 384) ? sigm(acc2) : tanh_f(acc2);
        }
        __syncthreads();

        const bool doTile = ((t & 31) == 30) && (t + 2 < SS);
        float4 xld; int Tn = 0;
        if (doTile) {
            Tn = (t + 2) >> 5;
            const int row = j >> 3, tc = j & 7;
            xld = *(const float4*)(xrow + (size_t)row * SS + TT * Tn + 4 * tc);
        }
        if (j < HH) {
            const float cn_new = actI[HH + j] * cnb[j] + actI[j] * actI[384 + j];
            const float c_new  = actI[2 * HH + j] * tanh_f(cn_new);
            const float h_new  = actO[2 * HH + j] * tanh_f(c_new);
            cnb[j] = cn_new;
            cb[j]  = c_new;
            ((_Float16*)hb)[j] = (_Float16)h_new;
        } else if (j < HH + 32) {
            const int m = j - HH;
            const int tn = t + 1;
            const int tbn = (tn >> 5) & 1, ttn = tn & 31;
            xb[tn & 1][m] = pack2(xt[tbn][2 * m][ttn],
                                  xt[tbn][2 * m + 1][ttn]);
        }
        if (doTile) {
            const int row = j >> 3, tc = j & 7;
            float* dst = &xt[Tn & 1][row][4 * tc];
            dst[0] = xld.x; dst[1] = xld.y; dst[2] = xld.z; dst[3] = xld.w;
        }
        __syncthreads();

        float p = 0.f;
#pragma unroll
        for (int q = 0; q < 2; ++q) {
            const int c = 2 * ps + q;
            F4H hu; hu.f4 = hb4[c];
            F4H wu; wu.f4 = wlf[c * 66 + pn];
            p = dot2(wu.h[0], hu.h[0], p);
            p = dot2(wu.h[1], hu.h[1], p);
            p = dot2(wu.h[2], hu.h[2], p);
            p = dot2(wu.h[3], hu.h[3], p);
        }
        p += __shfl_down(p, 4, 8);
        p += __shfl_down(p, 2, 8);
        p += __shfl_down(p, 1, 8);
        if (ps == 0) orow[t * OO + pn] = p + bl;
    }
}

extern "C" void kernel_launch(void* const* d_in, const int* in_sizes, int n_in,
                              void* d_out, int out_size, void* d_ws, size_t ws_size,
                              hipStream_t stream) {
    (void)in_sizes; (void)n_in; (void)out_size;
    const float* x      = (const float*)d_in[0];
    const float* Wx_out = (const float*)d_in[1];
    const float* Wh_out = (const float*)d_in[2];
    const float* b_out  = (const float*)d_in[3];
    const float* Wx_in  = (const float*)d_in[4];
    const float* Wh_in  = (const float*)d_in[5];
    const float* b_in   = (const float*)d_in[6];
    const float* W_lin  = (const float*)d_in[7];
    const float* b_lin  = (const float*)d_in[8];
    float* out = (float*)d_out;

    if (d_ws != nullptr && ws_size >= XPBYTES) {
        _Float16* xpw = (_Float16*)d_ws;
        xp_gemm<<<dim3(16, BB), dim3(512), 0, stream>>>(x, Wx_out, xpw);
        nlstm_scan_xp2<<<dim3(BB / 2), dim3(512), 0, stream>>>(
            xpw, Wh_out, b_out, Wx_in, Wh_in, b_in, W_lin, b_lin, out);
    } else {
        nlstm_scan<<<dim3(BB), dim3(512), 0, stream>>>(
            x, Wx_out, Wh_out, b_out, Wx_in, Wh_in, b_in, W_lin, b_lin, out);
    }
}

// Round 18
// 3515.763 us; speedup vs baseline: 1.9533x; 1.9533x over previous
//
#include <hip/hip_runtime.h>
#include <hip/hip_fp16.h>

#define BB 128
#define II 64
#define SS 2048
#define HH 128
#define GG 512   // 4*H
#define OO 64
#define TT 32    // x time-tile width (fallback kernel)
#define TCH 128  // precompute t-chunk
#define XPBYTES ((size_t)BB * SS * GG * 2)

typedef _Float16 f16x2 __attribute__((ext_vector_type(2)));
union F4H { float4 f4; f16x2 h[4]; };

__device__ __forceinline__ f16x2 pack2(float a, float b) {
    f16x2 r; r.x = (_Float16)a; r.y = (_Float16)b; return r;
}

__device__ __forceinline__ float dot2(f16x2 w, f16x2 v, float c) {
#if __has_builtin(__builtin_amdgcn_fdot2)
    return __builtin_amdgcn_fdot2(w, v, c, false);
#else
    return fmaf((float)w.x, (float)v.x, fmaf((float)w.y, (float)v.y, c));
#endif
}

__device__ __forceinline__ float sigm(float v) {
    return __builtin_amdgcn_rcpf(1.0f + __expf(-v));
}
// original tanh (fallback kernel keeps R1 bit-exact behavior)
__device__ __forceinline__ float tanh_f(float v) {
    float a = fabsf(v);
    float e = __expf(-2.0f * a);
    float r = (1.0f - e) * __builtin_amdgcn_rcpf(1.0f + e);
    return v < 0.0f ? -r : r;
}
// branch-free tanh = 2*sigm(2v)-1 (safe at +/-inf)
__device__ __forceinline__ float tanh_c(float v) {
    return fmaf(2.0f, __builtin_amdgcn_rcpf(1.0f + __expf(-2.0f * v)), -1.0f);
}

// quad-scope shuffle via DPP quad_perm (VALU pipe ~4cyc)
template <int CTRL>
__device__ __forceinline__ float qdpp(float x) {
    return __int_as_float(__builtin_amdgcn_update_dpp(
        0, __float_as_int(x), CTRL, 0xF, 0xF, true));
}
#define QP_XOR3 0x1B   // [3,2,1,0]
#define QP_BC0  0x00   // [0,0,0,0]
#define QP_BC1  0x55   // [1,1,1,1]
#define QP_BC2  0xAA   // [2,2,2,2]

// LDS-only barrier (R15): lgkmcnt(0) + raw s_barrier, no vmcnt drain —
// global loads/stores stay in flight across the barrier. Safe: the only
// cross-thread deps at these barriers are LDS writes (xib/hib at S1,
// hb at S2), fully fenced by lgkmcnt(0).
__device__ __forceinline__ void lds_barrier() {
    asm volatile("s_waitcnt lgkmcnt(0)" ::: "memory");
    __builtin_amdgcn_s_barrier();
}

// ============================================================================
// XP precompute: XP[b][t][j] = sum_i x[b,i,t] * Wx_out[i,j], stored f16.
// ============================================================================
__global__ void __launch_bounds__(512)
xp_gemm(const float* __restrict__ x, const float* __restrict__ Wx_out,
        _Float16* __restrict__ xp)
{
    const int tc = blockIdx.x;          // 0..15
    const int b  = blockIdx.y;          // 0..127
    const int j  = threadIdx.x;         // gate column 0..511
    const int t0 = tc * TCH;

    __shared__ __align__(16) f16x2 x2s[TCH][36];

    f16x2 w2[32];
#pragma unroll
    for (int c = 0; c < 32; ++c)
        w2[c] = pack2(Wx_out[(2 * c) * GG + j], Wx_out[(2 * c + 1) * GG + j]);

    const float* xrow = x + (size_t)b * II * SS;
    const int r = j >> 3;
#pragma unroll
    for (int rep = 0; rep < 4; ++rep) {
        const int u = (j & 7) + 8 * rep;
        const float4 v = *(const float4*)(xrow + (size_t)r * SS + t0 + 4 * u);
        const int c = r >> 1, half = r & 1;
        ((_Float16*)&x2s[4 * u + 0][c])[half] = (_Float16)v.x;
        ((_Float16*)&x2s[4 * u + 1][c])[half] = (_Float16)v.y;
        ((_Float16*)&x2s[4 * u + 2][c])[half] = (_Float16)v.z;
        ((_Float16*)&x2s[4 * u + 3][c])[half] = (_Float16)v.w;
    }
    __syncthreads();

    _Float16* xpo = xp + ((size_t)b * SS + t0) * GG + j;
#pragma unroll 4
    for (int tt = 0; tt < TCH; ++tt) {
        const float4* xr4 = (const float4*)&x2s[tt][0];
        float a0 = 0.f, a1 = 0.f;
#pragma unroll
        for (int q = 0; q < 8; ++q) {
            F4H u; u.f4 = xr4[q];
            a0 = dot2(w2[4 * q + 0], u.h[0], a0);
            a1 = dot2(w2[4 * q + 1], u.h[1], a1);
            a0 = dot2(w2[4 * q + 2], u.h[2], a0);
            a1 = dot2(w2[4 * q + 3], u.h[3], a1);
        }
        xpo[(size_t)tt * GG] = (_Float16)(a0 + a1);
    }
}

// ============================================================================
// Scan — FINAL (verified best, measured 3520-3531 us across R9/R12/R14/R15).
// Quad-gate layout: thread j owns gate g=j&3 of h-column m=j>>2
// (col = g*128+m); a lane-quad holds (i,f,o,g) of one column.
//   - elementwise phases are quad-local: DPP quad_perm + register math
//   - c/cn redundant in all 4 lanes -> update broadcasts independent
//   - 2 barriers/step (minimum: S1 protects A-tail->C, S2 protects C-tail->A)
//   - XP (input GEMM) hoisted to xp_gemm; phase A's x-part is 1 f16 load
//     prefetched a full step ahead
//   - lds_barrier (lgkmcnt-only) keeps global ops in flight across barriers
// STRUCTURAL CEILING (measured R17): VALU-active on working CUs saturates
// at ~55-60% in this structure (issue + LDS-broadcast contention at
// 2 waves/SIMD) — doubling per-wave work (2-batch unskewed, 64 blocks)
// costs 1.92x time for 2x work: no net gain. This config is at the limit.
// DO-NOT-TOUCH notes (all measured):
//   * REGISTER CLIFF (R8,R11): 192 weight regs on the 128-arch-VGPR budget
//     leaves ~0 allocator margin. Extra values live across the 128-dot2
//     phase C spill -> FETCH 173->800+ MB -> 6x regression.
//   * E PLACEMENT (R13): projection must stay post-S2. Moving it into
//     phase A's window caused +6600 stall cyc/step (2.6x) with NO spill.
//   * LDS-resident Wh_out is 4% slower (R10). MFMA restructure serializes
//     pipes (R5). Cross-block split pays HBM RTT (R3). Skewed 2-batch
//     doubles per-wave issue serially (R4).
// ============================================================================
__global__ void __launch_bounds__(512)
nlstm_scan_xp(
    const _Float16* __restrict__ xp,
    const float* __restrict__ Wh_out, const float* __restrict__ b_out,
    const float* __restrict__ Wx_in, const float* __restrict__ Wh_in,
    const float* __restrict__ b_in,
    const float* __restrict__ W_lin, const float* __restrict__ b_lin,
    float* __restrict__ out)
{
    const int b = blockIdx.x;
    const int j = threadIdx.x;
    const int g = j & 3;          // gate lane within quad: 0=i 1=f 2=o 3=g
    const int m = j >> 2;         // h-column 0..127
    const int col = g * 128 + m;  // gate column in canonical layout

    __shared__ __align__(16) float4 wlf[16 * 66];      // W_lin fp16, 16.5 KB
    __shared__ __align__(16) _Float16 hb[HH];          // h fp16
    __shared__ __align__(16) _Float16 xib[HH];         // x_in fp16
    __shared__ __align__(16) _Float16 hib[HH];         // h_in fp16

    // register-resident fp16 weights (column col) : 192 regs (overflow->AGPR,
    // measured free on gfx950 unified file — R10)
    f16x2 who[HH / 2], wxi[HH / 2], whi[HH / 2];
#pragma unroll
    for (int q = 0; q < HH / 2; ++q)
        who[q] = pack2(Wh_out[(2 * q) * GG + col], Wh_out[(2 * q + 1) * GG + col]);
#pragma unroll
    for (int q = 0; q < HH / 2; ++q)
        wxi[q] = pack2(Wx_in[(2 * q) * GG + col], Wx_in[(2 * q + 1) * GG + col]);
#pragma unroll
    for (int q = 0; q < HH / 2; ++q)
        whi[q] = pack2(Wh_in[(2 * q) * GG + col], Wh_in[(2 * q + 1) * GG + col]);

    const float bo = b_out[col];
    const float bi = b_in[col];
    // branch-free activation: g<3 -> sigm(x); g==3 -> tanh(x)=2*sigm(2x)-1
    const float kk = (g == 3) ? 2.0f : 1.0f;
    const float aa = (g == 3) ? 2.0f : 1.0f;
    const float cc = (g == 3) ? -1.0f : 0.0f;

    const int   pn = j >> 3;
    const int   ps = j & 7;
    const float bl = b_lin[pn];

    // W_lin -> LDS fp16 (1024 chunks, 2 per thread)
#pragma unroll
    for (int r = 0; r < 2; ++r) {
        const int mm = r * 512 + j;
        const int c = mm >> 6, n = mm & 63;
        F4H u;
#pragma unroll
        for (int q = 0; q < 4; ++q)
            u.h[q] = pack2(W_lin[n * HH + 8 * c + 2 * q],
                           W_lin[n * HH + 8 * c + 2 * q + 1]);
        wlf[c * 66 + n] = u.f4;
    }

    if (j < HH) { hb[j] = (_Float16)0.f; xib[j] = (_Float16)0.f; hib[j] = (_Float16)0.f; }
    float c_reg = 0.f, cn_reg = 0.f;   // redundant in all 4 quad lanes
    float o_all = 0.f;                 // outer o, broadcast each step
    __syncthreads();

    const _Float16* xpr = xp + (size_t)b * SS * GG + col;
    float* orow = out + (size_t)b * SS * OO;
    const float4* hb4 = (const float4*)hb;   // 16 chunks
    const float4* xi4 = (const float4*)xib;  // 16 chunks
    const float4* hi4 = (const float4*)hib;  // 16 chunks

    _Float16 xpc = xpr[0];

#pragma unroll 1
    for (int t = 0; t < SS; ++t) {
        // ---- phase A: outer gate for col = XP + h@Wh_out + b ----
        float a0 = bo + (float)xpc, a1 = 0.f, a2 = 0.f, a3 = 0.f;
#pragma unroll
        for (int c = 0; c < 16; ++c) {
            F4H hu; hu.f4 = hb4[c];
            a0 = dot2(who[4 * c + 0], hu.h[0], a0);
            a1 = dot2(who[4 * c + 1], hu.h[1], a1);
            a2 = dot2(who[4 * c + 2], hu.h[2], a2);
            a3 = dot2(who[4 * c + 3], hu.h[3], a3);
        }
        // prefetch next step's XP (stays in flight across S1)
        const _Float16 xpn = xpr[(size_t)((t + 1) & (SS - 1)) * GG];
        const float accA = (a0 + a1) + (a2 + a3);
        const float v = fmaf(aa, sigm(kk * accA), cc);   // i/f/o/g by lane
        // quad tail (DPP): x_in = i*g at lane0, h_in = f*c at lane1
        const float vg3 = qdpp<QP_XOR3>(v);   // lane0 <- g-value
        o_all = qdpp<QP_BC2>(v);              // everyone keeps outer o
        if (g == 0)      xib[m] = (_Float16)(v * vg3);
        else if (g == 1) hib[m] = (_Float16)(v * c_reg);  // c_reg redundant-valid
        lds_barrier();   // S1 (lgkmcnt-only)

        // ---- phase C: inner gate for col ----
        float c0 = bi, c1 = 0.f, c2 = 0.f, c3 = 0.f;
#pragma unroll
        for (int c = 0; c < 16; ++c) {
            F4H xu; xu.f4 = xi4[c];
            c0 = dot2(wxi[4 * c + 0], xu.h[0], c0);
            c1 = dot2(wxi[4 * c + 1], xu.h[1], c1);
            c2 = dot2(wxi[4 * c + 2], xu.h[2], c2);
            c3 = dot2(wxi[4 * c + 3], xu.h[3], c3);
        }
#pragma unroll
        for (int c = 0; c < 16; ++c) {
            F4H hu; hu.f4 = hi4[c];
            c0 = dot2(whi[4 * c + 0], hu.h[0], c0);
            c1 = dot2(whi[4 * c + 1], hu.h[1], c1);
            c2 = dot2(whi[4 * c + 2], hu.h[2], c2);
            c3 = dot2(whi[4 * c + 3], hu.h[3], c3);
        }
        const float accC = (c0 + c1) + (c2 + c3);
        const float u = fmaf(aa, sigm(kk * accC), cc);    // ii/fi/oi/gi by lane
        // quad tail (DPP, redundant update in all lanes; P/F/O independent):
        const float ug3 = qdpp<QP_XOR3>(u);
        const float p0  = u * ug3;                 // ii*gi valid at lanes 0,3
        const float P   = qdpp<QP_BC0>(p0);        // ii*gi everywhere
        const float F   = qdpp<QP_BC1>(u);         // fi everywhere
        const float O   = qdpp<QP_BC2>(u);         // oi everywhere
        const float cn_new = fmaf(F, cn_reg, P);
        cn_reg = cn_new;
        const float c_new = O * tanh_c(cn_new);
        c_reg = c_new;
        const float h_new = o_all * tanh_c(c_new);
        if (g == 2) hb[m] = (_Float16)h_new;
        xpc = xpn;
        lds_barrier();   // S2 (lgkmcnt-only)

        // ---- phase E: fused projection (post-S2 — the ONLY placement that
        //      works, measured R8/R11/R13; store retires under next A+C) ----
        float p = 0.f;
#pragma unroll
        for (int q = 0; q < 2; ++q) {
            const int c = 2 * ps + q;
            F4H hu; hu.f4 = hb4[c];
            F4H wu; wu.f4 = wlf[c * 66 + pn];
            p = dot2(wu.h[0], hu.h[0], p);
            p = dot2(wu.h[1], hu.h[1], p);
            p = dot2(wu.h[2], hu.h[2], p);
            p = dot2(wu.h[3], hu.h[3], p);
        }
        p += __shfl_down(p, 4, 8);
        p += __shfl_down(p, 2, 8);
        p += __shfl_down(p, 1, 8);
        if (ps == 0) orow[t * OO + pn] = p + bl;
    }
}

// ============================================================================
// FALLBACK: exact R1 kernel (measured 4364 us) for when ws is too small.
// ============================================================================
__global__ void
__attribute__((amdgpu_flat_work_group_size(512, 512)))
__attribute__((amdgpu_waves_per_eu(2, 2)))
nlstm_scan(
    const float* __restrict__ x,
    const float* __restrict__ Wx_out, const float* __restrict__ Wh_out,
    const float* __restrict__ b_out,
    const float* __restrict__ Wx_in, const float* __restrict__ Wh_in,
    const float* __restrict__ b_in,
    const float* __restrict__ W_lin, const float* __restrict__ b_lin,
    float* __restrict__ out)
{
    const int b = blockIdx.x;
    const int j = threadIdx.x;

    __shared__ __align__(16) float4 wxf[8 * 512];
    __shared__ __align__(16) float4 wlf[16 * 66];
    __shared__ float xt[2][II][TT + 1];
    __shared__ __align__(16) f16x2 xb[2][II / 2];
    __shared__ __align__(16) f16x2 hb[HH / 2];
    __shared__ __align__(16) f16x2 xib[HH / 2];
    __shared__ __align__(16) f16x2 hib[HH / 2];
    __shared__ float cb[HH];
    __shared__ float cnb[HH];
    __shared__ float actO[GG];
    __shared__ float actI[GG];

    f16x2 who[HH / 2], wxi[HH / 2], whi[HH / 2];
#pragma unroll
    for (int m = 0; m < HH / 2; ++m)
        who[m] = pack2(Wh_out[(2 * m) * GG + j], Wh_out[(2 * m + 1) * GG + j]);
#pragma unroll
    for (int m = 0; m < HH / 2; ++m)
        wxi[m] = pack2(Wx_in[(2 * m) * GG + j], Wx_in[(2 * m + 1) * GG + j]);
#pragma unroll
    for (int m = 0; m < HH / 2; ++m)
        whi[m] = pack2(Wh_in[(2 * m) * GG + j], Wh_in[(2 * m + 1) * GG + j]);

    const float bo = b_out[j];
    const float bi = b_in[j];
    const int   pn = j >> 3;
    const int   ps = j & 7;
    const float bl = b_lin[pn];

#pragma unroll
    for (int c = 0; c < 8; ++c) {
        F4H u;
#pragma unroll
        for (int q = 0; q < 4; ++q)
            u.h[q] = pack2(Wx_out[(8 * c + 2 * q) * GG + j],
                           Wx_out[(8 * c + 2 * q + 1) * GG + j]);
        wxf[c * 512 + j] = u.f4;
    }
#pragma unroll
    for (int r = 0; r < 2; ++r) {
        const int m = r * 512 + j;
        const int c = m >> 6, n = m & 63;
        F4H u;
#pragma unroll
        for (int q = 0; q < 4; ++q)
            u.h[q] = pack2(W_lin[n * HH + 8 * c + 2 * q],
                           W_lin[n * HH + 8 * c + 2 * q + 1]);
        wlf[c * 66 + n] = u.f4;
    }

    const float* xrow = x + (size_t)b * II * SS;
    float* orow = out + (size_t)b * SS * OO;

    {
        const int row = j >> 3, tc = j & 7;
        const float4 v = *(const float4*)(xrow + (size_t)row * SS + 4 * tc);
        float* dst = &xt[0][row][4 * tc];
        dst[0] = v.x; dst[1] = v.y; dst[2] = v.z; dst[3] = v.w;
    }
    if (j < HH / 2) hb[j] = pack2(0.f, 0.f);
    if (j < HH) { cb[j] = 0.f; cnb[j] = 0.f; }
    if (j >= 256 && j < 256 + 32) {
        const int m = j - 256;
        xb[0][m] = pack2(xrow[(2 * m) * SS], xrow[(2 * m + 1) * SS]);
    }
    __syncthreads();

    const float4* hb4 = (const float4*)hb;
    const float4* xi4 = (const float4*)xib;
    const float4* hi4 = (const float4*)hib;

#pragma unroll 1
    for (int t = 0; t < SS; ++t) {
        const float4* xcur = (const float4*)xb[t & 1];
        float a0 = bo, a1 = 0.f, a2 = 0.f, a3 = 0.f;
#pragma unroll
        for (int c = 0; c < 8; ++c) {
            F4H xu; xu.f4 = xcur[c];
            F4H wu; wu.f4 = wxf[c * 512 + j];
            a0 = dot2(wu.h[0], xu.h[0], a0);
            a1 = dot2(wu.h[1], xu.h[1], a1);
            a2 = dot2(wu.h[2], xu.h[2], a2);
            a3 = dot2(wu.h[3], xu.h[3], a3);
        }
#pragma unroll
        for (int c = 0; c < 16; ++c) {
            F4H hu; hu.f4 = hb4[c];
            a0 = dot2(who[4 * c + 0], hu.h[0], a0);
            a1 = dot2(who[4 * c + 1], hu.h[1], a1);
            a2 = dot2(who[4 * c + 2], hu.h[2], a2);
            a3 = dot2(who[4 * c + 3], hu.h[3], a3);
        }
        {
            const float acc = (a0 + a1) + (a2 + a3);
            actO[j] = (j < 384) ? sigm(acc) : tanh_f(acc);
        }
        __syncthreads();

        if (j < II) {
            xib[j] = pack2(actO[2 * j] * actO[384 + 2 * j],
                           actO[2 * j + 1] * actO[384 + 2 * j + 1]);
        } else if (j < II + HH / 2) {
            const int m = j - II;
            hib[m] = pack2(actO[HH + 2 * m] * cb[2 * m],
                           actO[HH + 2 * m + 1] * cb[2 * m + 1]);
        }
        __syncthreads();

        float c0 = bi, c1 = 0.f, c2 = 0.f, c3 = 0.f;
#pragma unroll
        for (int c = 0; c < 16; ++c) {
            F4H xu; xu.f4 = xi4[c];
            c0 = dot2(wxi[4 * c + 0], xu.h[0], c0);
            c1 = dot2(wxi[4 * c + 1], xu.h[1], c1);
            c2 = dot2(wxi[4 * c + 2], xu.h[2], c2);
            c3 = dot2(wxi[4 * c + 3], xu.h[3], c3);
        }
#pragma unroll
        for (int c = 0; c < 16; ++c) {
            F4H hu; hu.f4 = hi4[c];
            c0 = dot2(whi[4 * c + 0], hu.h[0], c0);
            c1 = dot2(whi[4 * c + 1], hu.h[1], c1);
            c2 = dot2(whi[4 * c + 2], hu.h[2], c2);
            c3 = dot2(whi[4 * c + 3], hu.h[3], c3);
        }
        {
            const float acc2 = (c0 + c1) + (c2 + c3);
            actI[j] = (j < 384) ? sigm(acc2) : tanh_f(acc2);
        }
        __syncthreads();

        const bool doTile = ((t & 31) == 30) && (t + 2 < SS);
        float4 xld; int Tn = 0;
        if (doTile) {
            Tn = (t + 2) >> 5;
            const int row = j >> 3, tc = j & 7;
            xld = *(const float4*)(xrow + (size_t)row * SS + TT * Tn + 4 * tc);
        }
        if (j < HH) {
            const float cn_new = actI[HH + j] * cnb[j] + actI[j] * actI[384 + j];
            const float c_new  = actI[2 * HH + j] * tanh_f(cn_new);
            const float h_new  = actO[2 * HH + j] * tanh_f(c_new);
            cnb[j] = cn_new;
            cb[j]  = c_new;
            ((_Float16*)hb)[j] = (_Float16)h_new;
        } else if (j < HH + 32) {
            const int m = j - HH;
            const int tn = t + 1;
            const int tbn = (tn >> 5) & 1, ttn = tn & 31;
            xb[tn & 1][m] = pack2(xt[tbn][2 * m][ttn],
                                  xt[tbn][2 * m + 1][ttn]);
        }
        if (doTile) {
            const int row = j >> 3, tc = j & 7;
            float* dst = &xt[Tn & 1][row][4 * tc];
            dst[0] = xld.x; dst[1] = xld.y; dst[2] = xld.z; dst[3] = xld.w;
        }
        __syncthreads();

        float p = 0.f;
#pragma unroll
        for (int q = 0; q < 2; ++q) {
            const int c = 2 * ps + q;
            F4H hu; hu.f4 = hb4[c];
            F4H wu; wu.f4 = wlf[c * 66 + pn];
            p = dot2(wu.h[0], hu.h[0], p);
            p = dot2(wu.h[1], hu.h[1], p);
            p = dot2(wu.h[2], hu.h[2], p);
            p = dot2(wu.h[3], hu.h[3], p);
        }
        p += __shfl_down(p, 4, 8);
        p += __shfl_down(p, 2, 8);
        p += __shfl_down(p, 1, 8);
        if (ps == 0) orow[t * OO + pn] = p + bl;
    }
}

extern "C" void kernel_launch(void* const* d_in, const int* in_sizes, int n_in,
                              void* d_out, int out_size, void* d_ws, size_t ws_size,
                              hipStream_t stream) {
    (void)in_sizes; (void)n_in; (void)out_size;
    const float* x      = (const float*)d_in[0];
    const float* Wx_out = (const float*)d_in[1];
    const float* Wh_out = (const float*)d_in[2];
    const float* b_out  = (const float*)d_in[3];
    const float* Wx_in  = (const float*)d_in[4];
    const float* Wh_in  = (const float*)d_in[5];
    const float* b_in   = (const float*)d_in[6];
    const float* W_lin  = (const float*)d_in[7];
    const float* b_lin  = (const float*)d_in[8];
    float* out = (float*)d_out;

    if (d_ws != nullptr && ws_size >= XPBYTES) {
        _Float16* xpw = (_Float16*)d_ws;
        xp_gemm<<<dim3(16, BB), dim3(512), 0, stream>>>(x, Wx_out, xpw);
        nlstm_scan_xp<<<dim3(BB), dim3(512), 0, stream>>>(
            xpw, Wh_out, b_out, Wx_in, Wh_in, b_in, W_lin, b_lin, out);
    } else {
        nlstm_scan<<<dim3(BB), dim3(512), 0, stream>>>(
            x, Wx_out, Wh_out, b_out, Wx_in, Wh_in, b_in, W_lin, b_lin, out);
    }
}